// Round 1
// baseline (3990.134 us; speedup 1.0000x reference)
//
#include <hip/hip_runtime.h>
#include <hip/hip_bf16.h>
#include <math.h>

// Problem constants
constexpr int Bn = 4, Cn = 256, Hn = 48, Wn = 48, HW = 2304;
constexpr int FWn = 25, Mn = 1200;          // rfft bins along W, tokens = 48*25
constexpr float ATT_SCALE = 0.17677669529663687f;  // 1/sqrt(32)

// ---------------- GroupNorm (32 groups of 8 ch) ----------------
__global__ void gn_kernel(const float* __restrict__ x, const float* __restrict__ gw,
                          const float* __restrict__ gb, float* __restrict__ y) {
  int bg = blockIdx.x;                       // b*32 + g
  const float* xp = x + (size_t)bg * 18432;  // 8*2304
  float* yp = y + (size_t)bg * 18432;
  float s = 0.f, ss = 0.f;
  for (int i = threadIdx.x; i < 18432; i += 256) { float v = xp[i]; s += v; ss += v * v; }
#pragma unroll
  for (int off = 32; off; off >>= 1) { s += __shfl_xor(s, off); ss += __shfl_xor(ss, off); }
  __shared__ float rs[4], rss[4];
  int wid = threadIdx.x >> 6;
  if ((threadIdx.x & 63) == 0) { rs[wid] = s; rss[wid] = ss; }
  __syncthreads();
  s = rs[0] + rs[1] + rs[2] + rs[3];
  ss = rss[0] + rss[1] + rss[2] + rss[3];
  float mean = s * (1.f / 18432.f);
  float var = ss * (1.f / 18432.f) - mean * mean;
  float inv = rsqrtf(var + 1e-5f);
  int g = bg & 31;
  for (int i = threadIdx.x; i < 18432; i += 256) {
    int c = (g << 3) + (i / 2304);
    yp[i] = (xp[i] - mean) * inv * gw[c] + gb[c];
  }
}

// ---------------- Depthwise 3x3, SAME ----------------
__global__ void dw3x3_kernel(const float* __restrict__ in, const float* __restrict__ wd,
                             float* __restrict__ out) {
  int bc = blockIdx.x;
  int c = bc & 255;
  const float* ip = in + (size_t)bc * HW;
  float* op = out + (size_t)bc * HW;
  float w[9];
#pragma unroll
  for (int k = 0; k < 9; ++k) w[k] = wd[c * 9 + k];
  for (int p = threadIdx.x; p < HW; p += 256) {
    int yy = p / 48, xx = p - yy * 48;
    float a = 0.f;
#pragma unroll
    for (int ky = 0; ky < 3; ++ky) {
      int y2 = yy + ky - 1;
      if ((unsigned)y2 < 48u) {
#pragma unroll
        for (int kx = 0; kx < 3; ++kx) {
          int x2 = xx + kx - 1;
          if ((unsigned)x2 < 48u) a += ip[y2 * 48 + x2] * w[ky * 3 + kx];
        }
      }
    }
    op[p] = a;
  }
}

// ---------------- Pointwise 1x1 conv (Cin=256), bias, optional residual ----------------
template <bool RES>
__global__ void pw_kernel(const float* __restrict__ in, size_t in_bs,
                          const float* __restrict__ Wm, const float* __restrict__ bias,
                          const float* __restrict__ res, size_t res_bs,
                          float* __restrict__ out, size_t out_bs) {
  __shared__ float sw[256][4];
  int tid = threadIdx.x;
  int o0 = blockIdx.y * 4;
  for (int i = tid; i < 1024; i += 256)
    sw[i & 255][i >> 8] = Wm[(size_t)(o0 + (i >> 8)) * 256 + (i & 255)];
  __syncthreads();
  int p0 = blockIdx.x * 1024 + tid * 4;
  if (p0 >= HW) return;
  int bi = blockIdx.z;
  const float* ip = in + (size_t)bi * in_bs + p0;
  float4 acc[4];
#pragma unroll
  for (int j = 0; j < 4; ++j) acc[j] = make_float4(0.f, 0.f, 0.f, 0.f);
  for (int c = 0; c < 256; ++c) {
    float4 xv = *(const float4*)(ip + (size_t)c * HW);
    float4 w4 = *(const float4*)(&sw[c][0]);
    acc[0].x += w4.x * xv.x; acc[0].y += w4.x * xv.y; acc[0].z += w4.x * xv.z; acc[0].w += w4.x * xv.w;
    acc[1].x += w4.y * xv.x; acc[1].y += w4.y * xv.y; acc[1].z += w4.y * xv.z; acc[1].w += w4.y * xv.w;
    acc[2].x += w4.z * xv.x; acc[2].y += w4.z * xv.y; acc[2].z += w4.z * xv.z; acc[2].w += w4.z * xv.w;
    acc[3].x += w4.w * xv.x; acc[3].y += w4.w * xv.y; acc[3].z += w4.w * xv.z; acc[3].w += w4.w * xv.w;
  }
#pragma unroll
  for (int j = 0; j < 4; ++j) {
    float4 a = acc[j];
    float bv = bias[o0 + j];
    a.x += bv; a.y += bv; a.z += bv; a.w += bv;
    if (RES) {
      float4 rv = *(const float4*)(res + (size_t)bi * res_bs + (size_t)(o0 + j) * HW + p0);
      a.x += rv.x; a.y += rv.y; a.z += rv.z; a.w += rv.w;
    }
    *(float4*)(out + (size_t)bi * out_bs + (size_t)(o0 + j) * HW + p0) = a;
  }
}

// ---------------- L2 norm over 256 channels, in place ----------------
__global__ void l2n_kernel(float* __restrict__ t, size_t bstride) {
  int p = blockIdx.x * 256 + threadIdx.x;
  float* q = t + (size_t)blockIdx.y * bstride + p;
  float ss = 0.f;
  for (int c = 0; c < 256; ++c) { float v = q[(size_t)c * HW]; ss += v * v; }
  float inv = 1.f / fmaxf(sqrtf(ss), 1e-12f);
  for (int c = 0; c < 256; ++c) q[(size_t)c * HW] *= inv;
}

// ---------------- rfft2 (ortho) + abs/angle; one block per (b,c) plane ----------------
__global__ void rfft2_kernel(const float* __restrict__ in, size_t bstride,
                             float* __restrict__ amp, float* __restrict__ pha) {
  int bc = blockIdx.x;
  int bi = bc >> 8, c = bc & 255;
  const float* ip = in + (size_t)bi * bstride + (size_t)c * HW;
  __shared__ float sx[2304];
  __shared__ float yr[1200], yi[1200];
  __shared__ float ct[48], st[48];
  int tid = threadIdx.x;
  if (tid < 48) {
    float a = 6.283185307179586f * (float)tid / 48.f;
    ct[tid] = cosf(a); st[tid] = sinf(a);
  }
  for (int i = tid; i < 2304; i += 256) sx[i] = ip[i];
  __syncthreads();
  // stage 1: along W -> 25 bins.  Y[h,u] = sum_w x * e^{-2pi i w u/48}
  for (int i = tid; i < 1200; i += 256) {
    int h = i / 25, u = i - h * 25;
    float cw = ct[u], sw = st[u];
    float cr = 1.f, ci = 0.f, ar = 0.f, ai = 0.f;
    const float* row = &sx[h * 48];
#pragma unroll 4
    for (int w = 0; w < 48; ++w) {
      float v = row[w];
      ar += v * cr; ai -= v * ci;
      float nr = cr * cw - ci * sw;
      ci = cr * sw + ci * cw; cr = nr;
    }
    yr[i] = ar; yi[i] = ai;
  }
  __syncthreads();
  // stage 2: along H (full 48).  Z[v,u] = sum_h Y[h,u] e^{-2pi i h v/48}, *1/48
  for (int i = tid; i < 1200; i += 256) {
    int v = i / 25, u = i - v * 25;
    float cw = ct[v], sw = st[v];
    float cr = 1.f, ci = 0.f, zr = 0.f, zi = 0.f;
#pragma unroll 4
    for (int h = 0; h < 48; ++h) {
      float a = yr[h * 25 + u], b = yi[h * 25 + u];
      zr += a * cr + b * ci;
      zi += b * cr - a * ci;
      float nr = cr * cw - ci * sw;
      ci = cr * sw + ci * cw; cr = nr;
    }
    zr *= (1.f / 48.f); zi *= (1.f / 48.f);
    amp[(size_t)bc * 1200 + i] = sqrtf(zr * zr + zi * zi);
    pha[(size_t)bc * 1200 + i] = atan2f(zi, zr);
  }
}

// ---------------- flash attention (fp32), one m per lane ----------------
__global__ void attn_kernel(const float* __restrict__ Qm, const float* __restrict__ Km,
                            const float* __restrict__ Vm, float* __restrict__ Om) {
  int m = blockIdx.x * 64 + threadIdx.x;
  int bh = blockIdx.y;
  const float* qp = Qm + (size_t)bh * 38400;
  const float* kp = Km + (size_t)bh * 38400;
  const float* vp = Vm + (size_t)bh * 38400;
  bool act = m < 1200;
  int mm = act ? m : 0;
  float qr[32];
#pragma unroll
  for (int c = 0; c < 32; ++c) qr[c] = qp[(size_t)c * 1200 + mm] * ATT_SCALE;
  __shared__ float sk[48][36], sv[48][36];
  float acc[32];
#pragma unroll
  for (int c = 0; c < 32; ++c) acc[c] = 0.f;
  float mx = -3.0e38f, l = 0.f;
  for (int n0 = 0; n0 < 1200; n0 += 48) {
    __syncthreads();
    for (int i = threadIdx.x; i < 1536; i += 64) {
      int cc = i / 48, nl = i - cc * 48;
      sk[nl][cc] = kp[(size_t)cc * 1200 + n0 + nl];
      sv[nl][cc] = vp[(size_t)cc * 1200 + n0 + nl];
    }
    __syncthreads();
    for (int nl = 0; nl < 48; ++nl) {
      const float4* k4p = (const float4*)&sk[nl][0];
      float s = 0.f;
#pragma unroll
      for (int c4 = 0; c4 < 8; ++c4) {
        float4 k4 = k4p[c4];
        s += qr[c4 * 4 + 0] * k4.x + qr[c4 * 4 + 1] * k4.y +
             qr[c4 * 4 + 2] * k4.z + qr[c4 * 4 + 3] * k4.w;
      }
      if (s > mx) {
        float r = __expf(mx - s);
        l *= r;
#pragma unroll
        for (int c = 0; c < 32; ++c) acc[c] *= r;
        mx = s;
      }
      float p = __expf(s - mx);
      l += p;
      const float4* v4p = (const float4*)&sv[nl][0];
#pragma unroll
      for (int c4 = 0; c4 < 8; ++c4) {
        float4 v4 = v4p[c4];
        acc[c4 * 4 + 0] += p * v4.x; acc[c4 * 4 + 1] += p * v4.y;
        acc[c4 * 4 + 2] += p * v4.z; acc[c4 * 4 + 3] += p * v4.w;
      }
    }
  }
  if (act) {
    float inv = 1.f / l;
#pragma unroll
    for (int c = 0; c < 32; ++c) Om[(size_t)bh * 38400 + (size_t)c * 1200 + m] = acc[c] * inv;
  }
}

// ---------------- polar + irfft2 (ortho); one block per (b,c) ----------------
__global__ void polar_irfft2_kernel(const float* __restrict__ amp, const float* __restrict__ pha,
                                    float* __restrict__ out) {
  int bc = blockIdx.x;
  __shared__ float zr[1200], zi[1200], yr[1200], yi[1200];
  __shared__ float ct[48], st[48];
  int tid = threadIdx.x;
  if (tid < 48) {
    float a = 6.283185307179586f * (float)tid / 48.f;
    ct[tid] = cosf(a); st[tid] = sinf(a);
  }
  for (int i = tid; i < 1200; i += 256) {
    float a = amp[(size_t)bc * 1200 + i];
    float p = pha[(size_t)bc * 1200 + i];
    zr[i] = a * cosf(p);
    zi[i] = a * sinf(p);
  }
  __syncthreads();
  // stage 1: complex inverse along H: Y[h,u] = sum_v Z[v,u] e^{+2pi i h v/48}; fold c_u/48
  for (int i = tid; i < 1200; i += 256) {
    int h = i / 25, u = i - h * 25;
    float cw = ct[h], sw = st[h];
    float cr = 1.f, ci = 0.f, sr = 0.f, si = 0.f;
#pragma unroll 4
    for (int v = 0; v < 48; ++v) {
      float a = zr[v * 25 + u], b = zi[v * 25 + u];
      sr += a * cr - b * ci;
      si += a * ci + b * cr;
      float nr = cr * cw - ci * sw;
      ci = cr * sw + ci * cw; cr = nr;
    }
    float sc = (u == 0 || u == 24) ? (1.f / 48.f) : (2.f / 48.f);
    yr[i] = sr * sc; yi[i] = si * sc;
  }
  __syncthreads();
  // stage 2: Hermitian inverse along W: x[h,w] = sum_u (Yr cos - Yi sin)
  for (int i = tid; i < 2304; i += 256) {
    int h = i / 48, w = i - h * 48;
    float cw = ct[w], sw = st[w];
    float cr = 1.f, ci = 0.f, s = 0.f;
#pragma unroll 5
    for (int u = 0; u < 25; ++u) {
      s += yr[h * 25 + u] * cr - yi[h * 25 + u] * ci;
      float nr = cr * cw - ci * sw;
      ci = cr * sw + ci * cw; cr = nr;
    }
    out[(size_t)bc * 2304 + i] = s;
  }
}

// ---------------- 3x3 conv, weights staged in LDS, 8o x 4px per thread ----------------
template <int CIN, bool SILU>
__global__ void conv3x3_kernel(const float* __restrict__ in, const float* __restrict__ Wt,
                               float* __restrict__ out, int Cout) {
  __shared__ float sw[16 * 9 * 36];
  int tid = threadIdx.x;
  int og = tid >> 6;        // 0..3 -> o-subgroup of 8
  int pq = tid & 63;        // 0..63 -> pixel quad
  int o32 = blockIdx.y * 32;
  int bi = blockIdx.z;
  int px = blockIdx.x * 256 + pq * 4;
  int yy = px / 48, x0 = px - yy * 48;
  float acc[8][4];
#pragma unroll
  for (int j = 0; j < 8; ++j)
#pragma unroll
    for (int q = 0; q < 4; ++q) acc[j][q] = 0.f;
  const float* ibase = in + (size_t)bi * CIN * HW;
  for (int c0 = 0; c0 < CIN; c0 += 16) {
    __syncthreads();
    for (int i = tid; i < 4608; i += 256) {
      int op = i / 144, r = i - op * 144;  // r = cbar*9 + k
      sw[r * 36 + op] = Wt[((size_t)(o32 + op) * CIN + c0) * 9 + r];
    }
    __syncthreads();
    for (int c = 0; c < 16; ++c) {
      const float* pl = ibase + (size_t)(c0 + c) * HW;
      float tap[3][6];
#pragma unroll
      for (int dy = 0; dy < 3; ++dy) {
        int y2 = yy + dy - 1;
        bool oky = (unsigned)y2 < 48u;
#pragma unroll
        for (int dx = 0; dx < 6; ++dx) {
          int x2 = x0 + dx - 1;
          tap[dy][dx] = (oky && (unsigned)x2 < 48u) ? pl[y2 * 48 + x2] : 0.f;
        }
      }
#pragma unroll
      for (int k = 0; k < 9; ++k) {
        const int ky = k / 3, kx = k - ky * 3;
        const float4 wa = *(const float4*)&sw[(c * 9 + k) * 36 + og * 8];
        const float4 wb = *(const float4*)&sw[(c * 9 + k) * 36 + og * 8 + 4];
        const float w8[8] = {wa.x, wa.y, wa.z, wa.w, wb.x, wb.y, wb.z, wb.w};
#pragma unroll
        for (int j = 0; j < 8; ++j)
#pragma unroll
          for (int q = 0; q < 4; ++q) acc[j][q] += w8[j] * tap[ky][kx + q];
      }
    }
  }
#pragma unroll
  for (int j = 0; j < 8; ++j) {
    int o = o32 + og * 8 + j;
    float4 r;
    r.x = acc[j][0]; r.y = acc[j][1]; r.z = acc[j][2]; r.w = acc[j][3];
    if (SILU) {
      r.x = r.x / (1.f + __expf(-r.x));
      r.y = r.y / (1.f + __expf(-r.y));
      r.z = r.z / (1.f + __expf(-r.z));
      r.w = r.w / (1.f + __expf(-r.w));
    }
    *(float4*)(out + ((size_t)bi * Cout + o) * HW + px) = r;
  }
}

extern "C" void kernel_launch(void* const* d_in, const int* in_sizes, int n_in,
                              void* d_out, int out_size, void* d_ws, size_t ws_size,
                              hipStream_t stream) {
  (void)in_sizes; (void)n_in; (void)out_size; (void)ws_size;
  const float* x      = (const float*)d_in[0];
  const float* cond   = (const float*)d_in[1];
  const float* gn_w   = (const float*)d_in[2];
  const float* gn_b   = (const float*)d_in[3];
  const float* q_dw   = (const float*)d_in[4];
  const float* q_pw_w = (const float*)d_in[5];
  const float* q_pw_b = (const float*)d_in[6];
  const float* kv_dw  = (const float*)d_in[7];
  const float* kv_pw_w= (const float*)d_in[8];
  const float* kv_pw_b= (const float*)d_in[9];
  const float* ao_w   = (const float*)d_in[10];
  const float* ao_b   = (const float*)d_in[11];
  const float* w1     = (const float*)d_in[12];
  const float* w2     = (const float*)d_in[13];
  const float* w3     = (const float*)d_in[14];
  const float* b3     = (const float*)d_in[15];
  float* ws = (float*)d_ws;
  float* Yo = (float*)d_out;

  const size_t U = 2359296;   // 4*256*48*48
  const size_t Hf = 1228800;  // 4*256*48*25
  const size_t CS = 589824;   // 256*2304
  const size_t CS2 = 1179648; // 512*2304

  float* XN  = ws;             // [0,U)       live: gn .. attn_out pw
  float* DW  = ws + U;         // [U,2U)      dw scratch; later OUT; later H2? (H2 at 0)
  float* Qb  = ws + 2 * U;     // [2U,3U)     q; later AO/PO; later H1 (2U..4U)
  float* KV  = ws + 3 * U;     // [3U,5U)
  float* AQ  = ws + 5 * U;     // 6 half-size spectra [5U, 5U+6Hf); later ATT at 5U
  float* PQ  = AQ + Hf;
  float* AK  = AQ + 2 * Hf;
  float* PK  = AQ + 3 * Hf;
  float* AV  = AQ + 4 * Hf;
  float* PV  = AQ + 5 * Hf;
  float* AO  = ws + 2 * U;     // overlaps dead Q
  float* PO  = AO + Hf;        // extends into dead K region
  float* OUT = ws + U;         // overlaps dead DW
  float* ATT = ws + 5 * U;     // overlaps dead AQ/PQ
  float* H1  = ws + 2 * U;     // [2U,4U) overlaps dead AO/PO/KV
  float* H2  = ws;             // overlaps dead XN

  // 1. GroupNorm
  gn_kernel<<<128, 256, 0, stream>>>(x, gn_w, gn_b, XN);
  // 2-3. q path
  dw3x3_kernel<<<1024, 256, 0, stream>>>(XN, q_dw, DW);
  pw_kernel<false><<<dim3(3, 64, 4), 256, 0, stream>>>(DW, CS, q_pw_w, q_pw_b, nullptr, 0, Qb, CS);
  // 4-5. kv path
  dw3x3_kernel<<<1024, 256, 0, stream>>>(cond, kv_dw, DW);
  pw_kernel<false><<<dim3(3, 128, 4), 256, 0, stream>>>(DW, CS, kv_pw_w, kv_pw_b, nullptr, 0, KV, CS2);
  // 6. L2 norm (q, k, v)
  l2n_kernel<<<dim3(9, 4), 256, 0, stream>>>(Qb, CS);
  l2n_kernel<<<dim3(9, 4), 256, 0, stream>>>(KV, CS2);
  l2n_kernel<<<dim3(9, 4), 256, 0, stream>>>(KV + CS, CS2);
  // 7. rfft2 + abs/angle
  rfft2_kernel<<<1024, 256, 0, stream>>>(Qb, CS, AQ, PQ);
  rfft2_kernel<<<1024, 256, 0, stream>>>(KV, CS2, AK, PK);
  rfft2_kernel<<<1024, 256, 0, stream>>>(KV + CS, CS2, AV, PV);
  // 8. attention on amplitude and phase
  attn_kernel<<<dim3(19, 32), 64, 0, stream>>>(AQ, AK, AV, AO);
  attn_kernel<<<dim3(19, 32), 64, 0, stream>>>(PQ, PK, PV, PO);
  // 9. polar + irfft2
  polar_irfft2_kernel<<<1024, 256, 0, stream>>>(AO, PO, OUT);
  // 10. attn_out = 1x1(out) + b + xn
  pw_kernel<true><<<dim3(3, 64, 4), 256, 0, stream>>>(OUT, CS, ao_w, ao_b, XN, CS, ATT, CS);
  // 11. h1 = silu(conv3x3 256->512)
  conv3x3_kernel<256, true><<<dim3(9, 16, 4), 256, 0, stream>>>(ATT, w1, H1, 512);
  // 12. h2 = conv3x3 512->256
  conv3x3_kernel<512, false><<<dim3(9, 8, 4), 256, 0, stream>>>(H1, w2, H2, 256);
  // 13. out = 1x1(h2) + b3 + attn_out
  pw_kernel<true><<<dim3(3, 64, 4), 256, 0, stream>>>(H2, CS, w3, b3, ATT, CS, Yo, CS);
}

// Round 2
// 1662.046 us; speedup vs baseline: 2.4007x; 2.4007x over previous
//
#include <hip/hip_runtime.h>
#include <hip/hip_bf16.h>
#include <math.h>

// Problem constants
constexpr int Bn = 4, Cn = 256, Hn = 48, Wn = 48, HW = 2304;
constexpr float ATT_SCALE = 0.17677669529663687f;  // 1/sqrt(32)

typedef __attribute__((ext_vector_type(8))) short bf16x8;
typedef __attribute__((ext_vector_type(4))) float f32x4;

// ---------------- GroupNorm (32 groups of 8 ch) ----------------
__global__ void gn_kernel(const float* __restrict__ x, const float* __restrict__ gw,
                          const float* __restrict__ gb, float* __restrict__ y) {
  int bg = blockIdx.x;                       // b*32 + g
  const float* xp = x + (size_t)bg * 18432;  // 8*2304
  float* yp = y + (size_t)bg * 18432;
  float s = 0.f, ss = 0.f;
  for (int i = threadIdx.x; i < 18432; i += 256) { float v = xp[i]; s += v; ss += v * v; }
#pragma unroll
  for (int off = 32; off; off >>= 1) { s += __shfl_xor(s, off); ss += __shfl_xor(ss, off); }
  __shared__ float rs[4], rss[4];
  int wid = threadIdx.x >> 6;
  if ((threadIdx.x & 63) == 0) { rs[wid] = s; rss[wid] = ss; }
  __syncthreads();
  s = rs[0] + rs[1] + rs[2] + rs[3];
  ss = rss[0] + rss[1] + rss[2] + rss[3];
  float mean = s * (1.f / 18432.f);
  float var = ss * (1.f / 18432.f) - mean * mean;
  float inv = rsqrtf(var + 1e-5f);
  int g = bg & 31;
  for (int i = threadIdx.x; i < 18432; i += 256) {
    int c = (g << 3) + (i / 2304);
    yp[i] = (xp[i] - mean) * inv * gw[c] + gb[c];
  }
}

// ---------------- Depthwise 3x3, SAME ----------------
__global__ void dw3x3_kernel(const float* __restrict__ in, const float* __restrict__ wd,
                             float* __restrict__ out) {
  int bc = blockIdx.x;
  int c = bc & 255;
  const float* ip = in + (size_t)bc * HW;
  float* op = out + (size_t)bc * HW;
  float w[9];
#pragma unroll
  for (int k = 0; k < 9; ++k) w[k] = wd[c * 9 + k];
  for (int p = threadIdx.x; p < HW; p += 256) {
    int yy = p / 48, xx = p - yy * 48;
    float a = 0.f;
#pragma unroll
    for (int ky = 0; ky < 3; ++ky) {
      int y2 = yy + ky - 1;
      if ((unsigned)y2 < 48u) {
#pragma unroll
        for (int kx = 0; kx < 3; ++kx) {
          int x2 = xx + kx - 1;
          if ((unsigned)x2 < 48u) a += ip[y2 * 48 + x2] * w[ky * 3 + kx];
        }
      }
    }
    op[p] = a;
  }
}

// ---------------- Pointwise 1x1 conv (Cin=256), bias, optional residual ----------------
template <bool RES>
__global__ void pw_kernel(const float* __restrict__ in, size_t in_bs,
                          const float* __restrict__ Wm, const float* __restrict__ bias,
                          const float* __restrict__ res, size_t res_bs,
                          float* __restrict__ out, size_t out_bs) {
  __shared__ float sw[256][4];
  int tid = threadIdx.x;
  int o0 = blockIdx.y * 4;
  for (int i = tid; i < 1024; i += 256)
    sw[i & 255][i >> 8] = Wm[(size_t)(o0 + (i >> 8)) * 256 + (i & 255)];
  __syncthreads();
  int p0 = blockIdx.x * 1024 + tid * 4;
  if (p0 >= HW) return;
  int bi = blockIdx.z;
  const float* ip = in + (size_t)bi * in_bs + p0;
  float4 acc[4];
#pragma unroll
  for (int j = 0; j < 4; ++j) acc[j] = make_float4(0.f, 0.f, 0.f, 0.f);
  for (int c = 0; c < 256; ++c) {
    float4 xv = *(const float4*)(ip + (size_t)c * HW);
    float4 w4 = *(const float4*)(&sw[c][0]);
    acc[0].x += w4.x * xv.x; acc[0].y += w4.x * xv.y; acc[0].z += w4.x * xv.z; acc[0].w += w4.x * xv.w;
    acc[1].x += w4.y * xv.x; acc[1].y += w4.y * xv.y; acc[1].z += w4.y * xv.z; acc[1].w += w4.y * xv.w;
    acc[2].x += w4.z * xv.x; acc[2].y += w4.z * xv.y; acc[2].z += w4.z * xv.z; acc[2].w += w4.z * xv.w;
    acc[3].x += w4.w * xv.x; acc[3].y += w4.w * xv.y; acc[3].z += w4.w * xv.z; acc[3].w += w4.w * xv.w;
  }
#pragma unroll
  for (int j = 0; j < 4; ++j) {
    float4 a = acc[j];
    float bv = bias[o0 + j];
    a.x += bv; a.y += bv; a.z += bv; a.w += bv;
    if (RES) {
      float4 rv = *(const float4*)(res + (size_t)bi * res_bs + (size_t)(o0 + j) * HW + p0);
      a.x += rv.x; a.y += rv.y; a.z += rv.z; a.w += rv.w;
    }
    *(float4*)(out + (size_t)bi * out_bs + (size_t)(o0 + j) * HW + p0) = a;
  }
}

// ---------------- L2 norm over 256 channels, in place ----------------
__global__ void l2n_kernel(float* __restrict__ t, size_t bstride) {
  int p = blockIdx.x * 256 + threadIdx.x;
  float* q = t + (size_t)blockIdx.y * bstride + p;
  float ss = 0.f;
  for (int c = 0; c < 256; ++c) { float v = q[(size_t)c * HW]; ss += v * v; }
  float inv = 1.f / fmaxf(sqrtf(ss), 1e-12f);
  for (int c = 0; c < 256; ++c) q[(size_t)c * HW] *= inv;
}

// ---------------- rfft2 (ortho) + abs/angle; one block per (b,c) plane ----------------
__global__ void rfft2_kernel(const float* __restrict__ in, size_t bstride,
                             float* __restrict__ amp, float* __restrict__ pha) {
  int bc = blockIdx.x;
  int bi = bc >> 8, c = bc & 255;
  const float* ip = in + (size_t)bi * bstride + (size_t)c * HW;
  __shared__ float sx[2304];
  __shared__ float yr[1200], yi[1200];
  __shared__ float ct[48], st[48];
  int tid = threadIdx.x;
  if (tid < 48) {
    float a = 6.283185307179586f * (float)tid / 48.f;
    ct[tid] = cosf(a); st[tid] = sinf(a);
  }
  for (int i = tid; i < 2304; i += 256) sx[i] = ip[i];
  __syncthreads();
  for (int i = tid; i < 1200; i += 256) {
    int h = i / 25, u = i - h * 25;
    float cw = ct[u], sw = st[u];
    float cr = 1.f, ci = 0.f, ar = 0.f, ai = 0.f;
    const float* row = &sx[h * 48];
#pragma unroll 4
    for (int w = 0; w < 48; ++w) {
      float v = row[w];
      ar += v * cr; ai -= v * ci;
      float nr = cr * cw - ci * sw;
      ci = cr * sw + ci * cw; cr = nr;
    }
    yr[i] = ar; yi[i] = ai;
  }
  __syncthreads();
  for (int i = tid; i < 1200; i += 256) {
    int v = i / 25, u = i - v * 25;
    float cw = ct[v], sw = st[v];
    float cr = 1.f, ci = 0.f, zr = 0.f, zi = 0.f;
#pragma unroll 4
    for (int h = 0; h < 48; ++h) {
      float a = yr[h * 25 + u], b = yi[h * 25 + u];
      zr += a * cr + b * ci;
      zi += b * cr - a * ci;
      float nr = cr * cw - ci * sw;
      ci = cr * sw + ci * cw; cr = nr;
    }
    zr *= (1.f / 48.f); zi *= (1.f / 48.f);
    amp[(size_t)bc * 1200 + i] = sqrtf(zr * zr + zi * zi);
    pha[(size_t)bc * 1200 + i] = atan2f(zi, zr);
  }
}

// ---------------- flash attention (fp32), one m per lane ----------------
__global__ void attn_kernel(const float* __restrict__ Qm, const float* __restrict__ Km,
                            const float* __restrict__ Vm, float* __restrict__ Om) {
  int m = blockIdx.x * 64 + threadIdx.x;
  int bh = blockIdx.y;
  const float* qp = Qm + (size_t)bh * 38400;
  const float* kp = Km + (size_t)bh * 38400;
  const float* vp = Vm + (size_t)bh * 38400;
  bool act = m < 1200;
  int mm = act ? m : 0;
  float qr[32];
#pragma unroll
  for (int c = 0; c < 32; ++c) qr[c] = qp[(size_t)c * 1200 + mm] * ATT_SCALE;
  __shared__ float sk[48][36], sv[48][36];
  float acc[32];
#pragma unroll
  for (int c = 0; c < 32; ++c) acc[c] = 0.f;
  float mx = -3.0e38f, l = 0.f;
  for (int n0 = 0; n0 < 1200; n0 += 48) {
    __syncthreads();
    for (int i = threadIdx.x; i < 1536; i += 64) {
      int cc = i / 48, nl = i - cc * 48;
      sk[nl][cc] = kp[(size_t)cc * 1200 + n0 + nl];
      sv[nl][cc] = vp[(size_t)cc * 1200 + n0 + nl];
    }
    __syncthreads();
    for (int nl = 0; nl < 48; ++nl) {
      const float4* k4p = (const float4*)&sk[nl][0];
      float s = 0.f;
#pragma unroll
      for (int c4 = 0; c4 < 8; ++c4) {
        float4 k4 = k4p[c4];
        s += qr[c4 * 4 + 0] * k4.x + qr[c4 * 4 + 1] * k4.y +
             qr[c4 * 4 + 2] * k4.z + qr[c4 * 4 + 3] * k4.w;
      }
      if (s > mx) {
        float r = __expf(mx - s);
        l *= r;
#pragma unroll
        for (int c = 0; c < 32; ++c) acc[c] *= r;
        mx = s;
      }
      float p = __expf(s - mx);
      l += p;
      const float4* v4p = (const float4*)&sv[nl][0];
#pragma unroll
      for (int c4 = 0; c4 < 8; ++c4) {
        float4 v4 = v4p[c4];
        acc[c4 * 4 + 0] += p * v4.x; acc[c4 * 4 + 1] += p * v4.y;
        acc[c4 * 4 + 2] += p * v4.z; acc[c4 * 4 + 3] += p * v4.w;
      }
    }
  }
  if (act) {
    float inv = 1.f / l;
#pragma unroll
    for (int c = 0; c < 32; ++c) Om[(size_t)bh * 38400 + (size_t)c * 1200 + m] = acc[c] * inv;
  }
}

// ---------------- polar + irfft2 (ortho); one block per (b,c) ----------------
__global__ void polar_irfft2_kernel(const float* __restrict__ amp, const float* __restrict__ pha,
                                    float* __restrict__ out) {
  int bc = blockIdx.x;
  __shared__ float zr[1200], zi[1200], yr[1200], yi[1200];
  __shared__ float ct[48], st[48];
  int tid = threadIdx.x;
  if (tid < 48) {
    float a = 6.283185307179586f * (float)tid / 48.f;
    ct[tid] = cosf(a); st[tid] = sinf(a);
  }
  for (int i = tid; i < 1200; i += 256) {
    float a = amp[(size_t)bc * 1200 + i];
    float p = pha[(size_t)bc * 1200 + i];
    zr[i] = a * cosf(p);
    zi[i] = a * sinf(p);
  }
  __syncthreads();
  for (int i = tid; i < 1200; i += 256) {
    int h = i / 25, u = i - h * 25;
    float cw = ct[h], sw = st[h];
    float cr = 1.f, ci = 0.f, sr = 0.f, si = 0.f;
#pragma unroll 4
    for (int v = 0; v < 48; ++v) {
      float a = zr[v * 25 + u], b = zi[v * 25 + u];
      sr += a * cr - b * ci;
      si += a * ci + b * cr;
      float nr = cr * cw - ci * sw;
      ci = cr * sw + ci * cw; cr = nr;
    }
    float sc = (u == 0 || u == 24) ? (1.f / 48.f) : (2.f / 48.f);
    yr[i] = sr * sc; yi[i] = si * sc;
  }
  __syncthreads();
  for (int i = tid; i < 2304; i += 256) {
    int h = i / 48, w = i - h * 48;
    float cw = ct[w], sw = st[w];
    float cr = 1.f, ci = 0.f, s = 0.f;
#pragma unroll 5
    for (int u = 0; u < 25; ++u) {
      s += yr[h * 25 + u] * cr - yi[h * 25 + u] * ci;
      float nr = cr * cw - ci * sw;
      ci = cr * sw + ci * cw; cr = nr;
    }
    out[(size_t)bc * 2304 + i] = s;
  }
}

// ---------------- pack ATT (f32 NCHW, 256ch) -> bf16 padded NHWC [b][50][50][256] ----------------
__global__ void packx_kernel(const float* __restrict__ in, __hip_bfloat16* __restrict__ xp) {
  int y = blockIdx.x;     // 0..47
  int b = blockIdx.y;     // 0..3
  int c = threadIdx.x;    // 0..255
  const float* ip = in + ((size_t)(b * 256 + c) * 48 + y) * 48;
  __hip_bfloat16* op = xp + ((size_t)(b * 50 + y + 1) * 50 + 1) * 256 + c;
  for (int x = 0; x < 48; ++x) op[x * 256] = __float2bfloat16(ip[x]);
}

// ---------------- pack weights f32 [O][CIN][9] -> bf16 [tap][O][CIN] ----------------
template <int CIN>
__global__ void packw_kernel(const float* __restrict__ w, __hip_bfloat16* __restrict__ wp, int O) {
  int t = blockIdx.x * 256 + threadIdx.x;   // o*CIN + c
  int o = t / CIN, c = t - o * CIN;
  if (o >= O) return;
#pragma unroll
  for (int tap = 0; tap < 9; ++tap)
    wp[((size_t)tap * O + o) * CIN + c] = __float2bfloat16(w[(size_t)t * 9 + tap]);
}

// ---------------- MFMA 3x3 conv: bf16 padded NHWC in, tap-decomposed GEMM ----------------
// Block: 256 thr = 4 waves. M-tile 64 (out ch), N-tile 128 px; wave owns M=64 x N=32.
// A frag (16x32): m=lane&15 (o), k=(lane>>4)*8+j (c). B frag (32x16): n=lane&15 (px), k same.
// TO_PAD: fuse SiLU, write bf16 padded NHWC [b][50][50][CO] (next conv's input).
// else:   write f32 NCHW.
template <int CIN, bool TO_PAD>
__global__ void __launch_bounds__(256)
mfconv3x3(const __hip_bfloat16* __restrict__ Xp, const __hip_bfloat16* __restrict__ Wp,
          __hip_bfloat16* __restrict__ Op, float* __restrict__ Of, int CO) {
  const int lane = threadIdx.x & 63;
  const int wv = threadIdx.x >> 6;
  const int lm = lane & 15;
  const int kg = lane >> 4;                 // 0..3
  const int o0 = blockIdx.x * 64;
  const int b = blockIdx.z;
  const int p0 = blockIdx.y * 128 + wv * 32;

  int px[2], yy[2], xx[2], poff[2];
#pragma unroll
  for (int g = 0; g < 2; ++g) {
    px[g] = p0 + g * 16 + lm;
    yy[g] = px[g] / 48; xx[g] = px[g] - yy[g] * 48;
    poff[g] = ((b * 50 + yy[g] + 1) * 50 + (xx[g] + 1)) * CIN + kg * 8;
  }

  f32x4 acc[4][2];
#pragma unroll
  for (int f = 0; f < 4; ++f)
#pragma unroll
    for (int g = 0; g < 2; ++g) acc[f][g] = (f32x4){0.f, 0.f, 0.f, 0.f};

  const __hip_bfloat16* Wbase = Wp + (size_t)(o0 + lm) * CIN + kg * 8;

  for (int tap = 0; tap < 9; ++tap) {
    const int dy = tap / 3 - 1, dx = tap - (tap / 3) * 3 - 1;
    const int toff = (dy * 50 + dx) * CIN;
    const __hip_bfloat16* Wt = Wbase + (size_t)tap * CO * CIN;
#pragma unroll 4
    for (int c0 = 0; c0 < CIN; c0 += 32) {
      bf16x8 a[4], bb[2];
#pragma unroll
      for (int f = 0; f < 4; ++f)
        a[f] = *(const bf16x8*)(Wt + f * 16 * CIN + c0);
#pragma unroll
      for (int g = 0; g < 2; ++g)
        bb[g] = *(const bf16x8*)(Xp + poff[g] + toff + c0);
#pragma unroll
      for (int f = 0; f < 4; ++f)
#pragma unroll
        for (int g = 0; g < 2; ++g)
          acc[f][g] = __builtin_amdgcn_mfma_f32_16x16x32_bf16(a[f], bb[g], acc[f][g], 0, 0, 0);
    }
  }

#pragma unroll
  for (int f = 0; f < 4; ++f)
#pragma unroll
    for (int g = 0; g < 2; ++g) {
#pragma unroll
      for (int r = 0; r < 4; ++r) {
        int o = o0 + f * 16 + kg * 4 + r;
        float v = acc[f][g][r];
        if (TO_PAD) {
          v = v / (1.f + __expf(-v));
          Op[((size_t)(b * 50 + yy[g] + 1) * 50 + (xx[g] + 1)) * CO + o] = __float2bfloat16(v);
        } else {
          Of[((size_t)b * CO + o) * HW + px[g]] = v;
        }
      }
    }
}

extern "C" void kernel_launch(void* const* d_in, const int* in_sizes, int n_in,
                              void* d_out, int out_size, void* d_ws, size_t ws_size,
                              hipStream_t stream) {
  (void)in_sizes; (void)n_in; (void)out_size; (void)ws_size;
  const float* x      = (const float*)d_in[0];
  const float* cond   = (const float*)d_in[1];
  const float* gn_w   = (const float*)d_in[2];
  const float* gn_b   = (const float*)d_in[3];
  const float* q_dw   = (const float*)d_in[4];
  const float* q_pw_w = (const float*)d_in[5];
  const float* q_pw_b = (const float*)d_in[6];
  const float* kv_dw  = (const float*)d_in[7];
  const float* kv_pw_w= (const float*)d_in[8];
  const float* kv_pw_b= (const float*)d_in[9];
  const float* ao_w   = (const float*)d_in[10];
  const float* ao_b   = (const float*)d_in[11];
  const float* w1     = (const float*)d_in[12];
  const float* w2     = (const float*)d_in[13];
  const float* w3     = (const float*)d_in[14];
  const float* b3     = (const float*)d_in[15];
  float* ws = (float*)d_ws;
  float* Yo = (float*)d_out;

  const size_t U = 2359296;   // 4*256*48*48
  const size_t Hf = 1228800;  // 4*256*48*25
  const size_t CS = 589824;   // 256*2304
  const size_t CS2 = 1179648; // 512*2304

  float* XN  = ws;             // [0,U)
  float* DW  = ws + U;
  float* Qb  = ws + 2 * U;
  float* KV  = ws + 3 * U;     // 2U extent
  float* AQ  = ws + 5 * U;     // 6 spectra
  float* PQ  = AQ + Hf;
  float* AK  = AQ + 2 * Hf;
  float* PK  = AQ + 3 * Hf;
  float* AV  = AQ + 4 * Hf;
  float* PV  = AQ + 5 * Hf;
  float* AO  = ws + 2 * U;
  float* PO  = AO + Hf;
  float* OUT = ws + U;
  float* ATT = ws + 5 * U;     // [5U,6U)
  // FFN region (everything in [0,5U) except nothing live but ATT at 5U):
  __hip_bfloat16* Xp1 = (__hip_bfloat16*)(ws + U);                 // 2,560,000 bf16 (5.12 MB)
  __hip_bfloat16* Xp2 = (__hip_bfloat16*)(ws + 2 * U);             // 5,120,000 bf16 (10.24 MB)
  __hip_bfloat16* Wp1 = (__hip_bfloat16*)(ws + 2 * U + 2600000);   // 1,179,648 bf16
  __hip_bfloat16* Wp2 = (__hip_bfloat16*)(ws + 2 * U + 3200000);   // 1,179,648 bf16
  float* H2  = ws;                                                  // f32 NCHW

  // 1. GroupNorm
  gn_kernel<<<128, 256, 0, stream>>>(x, gn_w, gn_b, XN);
  // 2-3. q path
  dw3x3_kernel<<<1024, 256, 0, stream>>>(XN, q_dw, DW);
  pw_kernel<false><<<dim3(3, 64, 4), 256, 0, stream>>>(DW, CS, q_pw_w, q_pw_b, nullptr, 0, Qb, CS);
  // 4-5. kv path
  dw3x3_kernel<<<1024, 256, 0, stream>>>(cond, kv_dw, DW);
  pw_kernel<false><<<dim3(3, 128, 4), 256, 0, stream>>>(DW, CS, kv_pw_w, kv_pw_b, nullptr, 0, KV, CS2);
  // 6. L2 norm (q, k, v)
  l2n_kernel<<<dim3(9, 4), 256, 0, stream>>>(Qb, CS);
  l2n_kernel<<<dim3(9, 4), 256, 0, stream>>>(KV, CS2);
  l2n_kernel<<<dim3(9, 4), 256, 0, stream>>>(KV + CS, CS2);
  // 7. rfft2 + abs/angle
  rfft2_kernel<<<1024, 256, 0, stream>>>(Qb, CS, AQ, PQ);
  rfft2_kernel<<<1024, 256, 0, stream>>>(KV, CS2, AK, PK);
  rfft2_kernel<<<1024, 256, 0, stream>>>(KV + CS, CS2, AV, PV);
  // 8. attention on amplitude and phase
  attn_kernel<<<dim3(19, 32), 64, 0, stream>>>(AQ, AK, AV, AO);
  attn_kernel<<<dim3(19, 32), 64, 0, stream>>>(PQ, PK, PV, PO);
  // 9. polar + irfft2
  polar_irfft2_kernel<<<1024, 256, 0, stream>>>(AO, PO, OUT);
  // 10. attn_out = 1x1(out) + b + xn  -> ATT
  pw_kernel<true><<<dim3(3, 64, 4), 256, 0, stream>>>(OUT, CS, ao_w, ao_b, XN, CS, ATT, CS);
  // 11. FFN via bf16 MFMA: pack inputs/weights, then two tap-decomposed GEMM convs
  hipMemsetAsync(Xp1, 0, 2560000 * sizeof(__hip_bfloat16), stream);
  hipMemsetAsync(Xp2, 0, 5120000 * sizeof(__hip_bfloat16), stream);
  packx_kernel<<<dim3(48, 4), 256, 0, stream>>>(ATT, Xp1);
  packw_kernel<256><<<512, 256, 0, stream>>>(w1, Wp1, 512);
  packw_kernel<512><<<512, 256, 0, stream>>>(w2, Wp2, 256);
  // h1 = silu(conv3x3 256->512) -> bf16 padded NHWC
  mfconv3x3<256, true><<<dim3(8, 18, 4), 256, 0, stream>>>(Xp1, Wp1, Xp2, nullptr, 512);
  // h2 = conv3x3 512->256 -> f32 NCHW
  mfconv3x3<512, false><<<dim3(4, 18, 4), 256, 0, stream>>>(Xp2, Wp2, nullptr, H2, 256);
  // 12. out = 1x1(h2) + b3 + attn_out
  pw_kernel<true><<<dim3(3, 64, 4), 256, 0, stream>>>(H2, CS, w3, b3, ATT, CS, Yo, CS);
}

// Round 3
// 917.981 us; speedup vs baseline: 4.3466x; 1.8105x over previous
//
#include <hip/hip_runtime.h>
#include <hip/hip_bf16.h>
#include <math.h>

// Problem constants
constexpr int Bn = 4, Cn = 256, Hn = 48, Wn = 48, HW = 2304;
constexpr float ATT_SCALE = 0.17677669529663687f;  // 1/sqrt(32)

typedef __attribute__((ext_vector_type(8))) short bf16x8;
typedef __attribute__((ext_vector_type(4))) float f32x4;

// ---------------- GroupNorm (32 groups of 8 ch) ----------------
__global__ void gn_kernel(const float* __restrict__ x, const float* __restrict__ gw,
                          const float* __restrict__ gb, float* __restrict__ y) {
  int bg = blockIdx.x;                       // b*32 + g
  const float* xp = x + (size_t)bg * 18432;  // 8*2304
  float* yp = y + (size_t)bg * 18432;
  float s = 0.f, ss = 0.f;
  for (int i = threadIdx.x; i < 18432; i += 256) { float v = xp[i]; s += v; ss += v * v; }
#pragma unroll
  for (int off = 32; off; off >>= 1) { s += __shfl_xor(s, off); ss += __shfl_xor(ss, off); }
  __shared__ float rs[4], rss[4];
  int wid = threadIdx.x >> 6;
  if ((threadIdx.x & 63) == 0) { rs[wid] = s; rss[wid] = ss; }
  __syncthreads();
  s = rs[0] + rs[1] + rs[2] + rs[3];
  ss = rss[0] + rss[1] + rss[2] + rss[3];
  float mean = s * (1.f / 18432.f);
  float var = ss * (1.f / 18432.f) - mean * mean;
  float inv = rsqrtf(var + 1e-5f);
  int g = bg & 31;
  for (int i = threadIdx.x; i < 18432; i += 256) {
    int c = (g << 3) + (i / 2304);
    yp[i] = (xp[i] - mean) * inv * gw[c] + gb[c];
  }
}

// ---------------- Depthwise 3x3, SAME ----------------
__global__ void dw3x3_kernel(const float* __restrict__ in, const float* __restrict__ wd,
                             float* __restrict__ out) {
  int bc = blockIdx.x;
  int c = bc & 255;
  const float* ip = in + (size_t)bc * HW;
  float* op = out + (size_t)bc * HW;
  float w[9];
#pragma unroll
  for (int k = 0; k < 9; ++k) w[k] = wd[c * 9 + k];
  for (int p = threadIdx.x; p < HW; p += 256) {
    int yy = p / 48, xx = p - yy * 48;
    float a = 0.f;
#pragma unroll
    for (int ky = 0; ky < 3; ++ky) {
      int y2 = yy + ky - 1;
      if ((unsigned)y2 < 48u) {
#pragma unroll
        for (int kx = 0; kx < 3; ++kx) {
          int x2 = xx + kx - 1;
          if ((unsigned)x2 < 48u) a += ip[y2 * 48 + x2] * w[ky * 3 + kx];
        }
      }
    }
    op[p] = a;
  }
}

// ---------------- Pointwise 1x1 conv (Cin=256), bias, optional residual ----------------
template <bool RES>
__global__ void pw_kernel(const float* __restrict__ in, size_t in_bs,
                          const float* __restrict__ Wm, const float* __restrict__ bias,
                          const float* __restrict__ res, size_t res_bs,
                          float* __restrict__ out, size_t out_bs) {
  __shared__ float sw[256][4];
  int tid = threadIdx.x;
  int o0 = blockIdx.y * 4;
  for (int i = tid; i < 1024; i += 256)
    sw[i & 255][i >> 8] = Wm[(size_t)(o0 + (i >> 8)) * 256 + (i & 255)];
  __syncthreads();
  int p0 = blockIdx.x * 1024 + tid * 4;
  if (p0 >= HW) return;
  int bi = blockIdx.z;
  const float* ip = in + (size_t)bi * in_bs + p0;
  float4 acc[4];
#pragma unroll
  for (int j = 0; j < 4; ++j) acc[j] = make_float4(0.f, 0.f, 0.f, 0.f);
  for (int c = 0; c < 256; ++c) {
    float4 xv = *(const float4*)(ip + (size_t)c * HW);
    float4 w4 = *(const float4*)(&sw[c][0]);
    acc[0].x += w4.x * xv.x; acc[0].y += w4.x * xv.y; acc[0].z += w4.x * xv.z; acc[0].w += w4.x * xv.w;
    acc[1].x += w4.y * xv.x; acc[1].y += w4.y * xv.y; acc[1].z += w4.y * xv.z; acc[1].w += w4.y * xv.w;
    acc[2].x += w4.z * xv.x; acc[2].y += w4.z * xv.y; acc[2].z += w4.z * xv.z; acc[2].w += w4.z * xv.w;
    acc[3].x += w4.w * xv.x; acc[3].y += w4.w * xv.y; acc[3].z += w4.w * xv.z; acc[3].w += w4.w * xv.w;
  }
#pragma unroll
  for (int j = 0; j < 4; ++j) {
    float4 a = acc[j];
    float bv = bias[o0 + j];
    a.x += bv; a.y += bv; a.z += bv; a.w += bv;
    if (RES) {
      float4 rv = *(const float4*)(res + (size_t)bi * res_bs + (size_t)(o0 + j) * HW + p0);
      a.x += rv.x; a.y += rv.y; a.z += rv.z; a.w += rv.w;
    }
    *(float4*)(out + (size_t)bi * out_bs + (size_t)(o0 + j) * HW + p0) = a;
  }
}

// ---------------- L2 norm over 256 channels, in place ----------------
__global__ void l2n_kernel(float* __restrict__ t, size_t bstride) {
  int p = blockIdx.x * 256 + threadIdx.x;
  float* q = t + (size_t)blockIdx.y * bstride + p;
  float ss = 0.f;
  for (int c = 0; c < 256; ++c) { float v = q[(size_t)c * HW]; ss += v * v; }
  float inv = 1.f / fmaxf(sqrtf(ss), 1e-12f);
  for (int c = 0; c < 256; ++c) q[(size_t)c * HW] *= inv;
}

// ---------------- rfft2 (ortho) + abs/angle -> bf16; one block per (b,c) plane ----------------
// TLAY: token-major [bh][1200][32] (for Q,K of attention). else channel-major [bc][1200] (for V).
template <bool TLAY>
__global__ void rfft2_kernel(const float* __restrict__ in, size_t bstride,
                             __hip_bfloat16* __restrict__ amp, __hip_bfloat16* __restrict__ pha) {
  int bc = blockIdx.x;
  int bi = bc >> 8, c = bc & 255;
  const float* ip = in + (size_t)bi * bstride + (size_t)c * HW;
  __shared__ float sx[2304];
  __shared__ float yr[1200], yi[1200];
  __shared__ float ct[48], st[48];
  int tid = threadIdx.x;
  if (tid < 48) {
    float a = 6.283185307179586f * (float)tid / 48.f;
    ct[tid] = cosf(a); st[tid] = sinf(a);
  }
  for (int i = tid; i < 2304; i += 256) sx[i] = ip[i];
  __syncthreads();
  for (int i = tid; i < 1200; i += 256) {
    int h = i / 25, u = i - h * 25;
    float cw = ct[u], sw = st[u];
    float cr = 1.f, ci = 0.f, ar = 0.f, ai = 0.f;
    const float* row = &sx[h * 48];
#pragma unroll 4
    for (int w = 0; w < 48; ++w) {
      float v = row[w];
      ar += v * cr; ai -= v * ci;
      float nr = cr * cw - ci * sw;
      ci = cr * sw + ci * cw; cr = nr;
    }
    yr[i] = ar; yi[i] = ai;
  }
  __syncthreads();
  for (int i = tid; i < 1200; i += 256) {
    int v = i / 25, u = i - v * 25;
    float cw = ct[v], sw = st[v];
    float cr = 1.f, ci = 0.f, zr = 0.f, zi = 0.f;
#pragma unroll 4
    for (int h = 0; h < 48; ++h) {
      float a = yr[h * 25 + u], b = yi[h * 25 + u];
      zr += a * cr + b * ci;
      zi += b * cr - a * ci;
      float nr = cr * cw - ci * sw;
      ci = cr * sw + ci * cw; cr = nr;
    }
    zr *= (1.f / 48.f); zi *= (1.f / 48.f);
    float am = sqrtf(zr * zr + zi * zi);
    float ph = atan2f(zi, zr);
    size_t o;
    if (TLAY) o = ((size_t)(bc >> 5) * 1200 + i) * 32 + (bc & 31);
    else      o = (size_t)bc * 1200 + i;
    amp[o] = __float2bfloat16(am);
    pha[o] = __float2bfloat16(ph);
  }
}

// ---------------- MFMA attention, two-pass (max recompute) ----------------
// Q,K: bf16 [bh][1200][32]; V: bf16 [bh][32][1200]; O: f32 [bh][32][1200]
// 1 wave per block, m-tile = 16. Pass A: row max via mfma(K,Q) (D[n][m], col m = lane&15).
// Pass B: recompute scores per 32-n step, P = exp2(d*C - mx*C) -> LDS [16][40] bf16 ->
// A-frag for PV mfma; unnormalized accumulate, divide by wave-reduced sum at epilogue.
__global__ void __launch_bounds__(64)
attn_mfma(const __hip_bfloat16* __restrict__ Qt, const __hip_bfloat16* __restrict__ Kt,
          const __hip_bfloat16* __restrict__ Vc, float* __restrict__ Om) {
  const int bh = blockIdx.y;
  const int m0 = blockIdx.x * 16;
  const int lane = threadIdx.x;
  const int lm = lane & 15, kg = lane >> 4;
  __shared__ unsigned short Pl[16][40];
  __shared__ float linv[16];
  const __hip_bfloat16* Qp = Qt + ((size_t)bh * 1200 + m0) * 32;
  const __hip_bfloat16* Kp = Kt + (size_t)bh * 38400;
  const __hip_bfloat16* Vp = Vc + (size_t)bh * 38400;
  const bf16x8 qf = *(const bf16x8*)(Qp + lm * 32 + kg * 8);

  // pass A: row max of raw scores (scale folded later; C > 0 so monotone)
  float mx = -3.0e38f;
  for (int n0 = 0; n0 < 1200; n0 += 16) {
    bf16x8 kf = *(const bf16x8*)(Kp + (size_t)(n0 + lm) * 32 + kg * 8);
    f32x4 d = {0.f, 0.f, 0.f, 0.f};
    d = __builtin_amdgcn_mfma_f32_16x16x32_bf16(kf, qf, d, 0, 0, 0);
    mx = fmaxf(mx, fmaxf(fmaxf(d[0], d[1]), fmaxf(d[2], d[3])));
  }
  mx = fmaxf(mx, __shfl_xor(mx, 16));
  mx = fmaxf(mx, __shfl_xor(mx, 32));
  const float Cs = ATT_SCALE * 1.44269504f;   // scale * log2(e)
  const float mxl = mx * Cs;

  // pass B
  f32x4 acc0 = {0.f, 0.f, 0.f, 0.f}, acc1 = {0.f, 0.f, 0.f, 0.f};
  float psum = 0.f;
  for (int g = 0; g < 38; ++g) {
    const int n0 = g * 32;
#pragma unroll
    for (int t = 0; t < 2; ++t) {
      const int nn = n0 + t * 16;
      ushort4 pk;
      if (nn < 1200) {
        bf16x8 kf = *(const bf16x8*)(Kp + (size_t)(nn + lm) * 32 + kg * 8);
        f32x4 d = {0.f, 0.f, 0.f, 0.f};
        d = __builtin_amdgcn_mfma_f32_16x16x32_bf16(kf, qf, d, 0, 0, 0);
        float p0 = exp2f(d[0] * Cs - mxl), p1 = exp2f(d[1] * Cs - mxl);
        float p2 = exp2f(d[2] * Cs - mxl), p3 = exp2f(d[3] * Cs - mxl);
        psum += p0 + p1 + p2 + p3;
        pk.x = __builtin_bit_cast(unsigned short, __float2bfloat16(p0));
        pk.y = __builtin_bit_cast(unsigned short, __float2bfloat16(p1));
        pk.z = __builtin_bit_cast(unsigned short, __float2bfloat16(p2));
        pk.w = __builtin_bit_cast(unsigned short, __float2bfloat16(p3));
      } else {
        pk.x = pk.y = pk.z = pk.w = 0;
      }
      // lane holds col m=lm, rows nn + kg*4 + r  -> P[lm][t*16 + kg*4 + r]
      *(ushort4*)(&Pl[lm][t * 16 + kg * 4]) = pk;
    }
    // A-frag: P[m=lm][kg*8 .. +8]; B-frags: V[c][n0 + kg*8 .. +8]
    bf16x8 pa = *(const bf16x8*)(&Pl[lm][kg * 8]);
    bf16x8 v0 = *(const bf16x8*)(Vp + (size_t)lm * 1200 + n0 + kg * 8);
    bf16x8 v1 = *(const bf16x8*)(Vp + (size_t)(16 + lm) * 1200 + n0 + kg * 8);
    acc0 = __builtin_amdgcn_mfma_f32_16x16x32_bf16(pa, v0, acc0, 0, 0, 0);
    acc1 = __builtin_amdgcn_mfma_f32_16x16x32_bf16(pa, v1, acc1, 0, 0, 0);
  }
  psum += __shfl_xor(psum, 16);
  psum += __shfl_xor(psum, 32);
  if (kg == 0) linv[lm] = 1.f / psum;
  __syncthreads();
  // D[m][c]: col c = lm (+0/16), rows m = kg*4 + r
#pragma unroll
  for (int r = 0; r < 4; ++r) {
    int m = m0 + kg * 4 + r;
    float li = linv[kg * 4 + r];
    Om[(size_t)bh * 38400 + (size_t)lm * 1200 + m] = acc0[r] * li;
    Om[(size_t)bh * 38400 + (size_t)(16 + lm) * 1200 + m] = acc1[r] * li;
  }
}

// ---------------- polar + irfft2 (ortho); one block per (b,c) ----------------
__global__ void polar_irfft2_kernel(const float* __restrict__ amp, const float* __restrict__ pha,
                                    float* __restrict__ out) {
  int bc = blockIdx.x;
  __shared__ float zr[1200], zi[1200], yr[1200], yi[1200];
  __shared__ float ct[48], st[48];
  int tid = threadIdx.x;
  if (tid < 48) {
    float a = 6.283185307179586f * (float)tid / 48.f;
    ct[tid] = cosf(a); st[tid] = sinf(a);
  }
  for (int i = tid; i < 1200; i += 256) {
    float a = amp[(size_t)bc * 1200 + i];
    float p = pha[(size_t)bc * 1200 + i];
    zr[i] = a * cosf(p);
    zi[i] = a * sinf(p);
  }
  __syncthreads();
  for (int i = tid; i < 1200; i += 256) {
    int h = i / 25, u = i - h * 25;
    float cw = ct[h], sw = st[h];
    float cr = 1.f, ci = 0.f, sr = 0.f, si = 0.f;
#pragma unroll 4
    for (int v = 0; v < 48; ++v) {
      float a = zr[v * 25 + u], b = zi[v * 25 + u];
      sr += a * cr - b * ci;
      si += a * ci + b * cr;
      float nr = cr * cw - ci * sw;
      ci = cr * sw + ci * cw; cr = nr;
    }
    float sc = (u == 0 || u == 24) ? (1.f / 48.f) : (2.f / 48.f);
    yr[i] = sr * sc; yi[i] = si * sc;
  }
  __syncthreads();
  for (int i = tid; i < 2304; i += 256) {
    int h = i / 48, w = i - h * 48;
    float cw = ct[w], sw = st[w];
    float cr = 1.f, ci = 0.f, s = 0.f;
#pragma unroll 5
    for (int u = 0; u < 25; ++u) {
      s += yr[h * 25 + u] * cr - yi[h * 25 + u] * ci;
      float nr = cr * cw - ci * sw;
      ci = cr * sw + ci * cw; cr = nr;
    }
    out[(size_t)bc * 2304 + i] = s;
  }
}

// ---------------- pack ATT (f32 NCHW, 256ch) -> bf16 padded NHWC [b][50][50][256] ----------------
__global__ void packx_kernel(const float* __restrict__ in, __hip_bfloat16* __restrict__ xp) {
  int y = blockIdx.x;     // 0..47
  int b = blockIdx.y;     // 0..3
  int c = threadIdx.x;    // 0..255
  const float* ip = in + ((size_t)(b * 256 + c) * 48 + y) * 48;
  __hip_bfloat16* op = xp + ((size_t)(b * 50 + y + 1) * 50 + 1) * 256 + c;
  for (int x = 0; x < 48; ++x) op[x * 256] = __float2bfloat16(ip[x]);
}

// ---------------- pack weights f32 [O][CIN][9] -> bf16 [tap][O][CIN] ----------------
template <int CIN>
__global__ void packw_kernel(const float* __restrict__ w, __hip_bfloat16* __restrict__ wp, int O) {
  int t = blockIdx.x * 256 + threadIdx.x;   // o*CIN + c
  int o = t / CIN, c = t - o * CIN;
  if (o >= O) return;
#pragma unroll
  for (int tap = 0; tap < 9; ++tap)
    wp[((size_t)tap * O + o) * CIN + c] = __float2bfloat16(w[(size_t)t * 9 + tap]);
}

// ---------------- MFMA 3x3 conv: bf16 padded NHWC in, tap-decomposed GEMM ----------------
template <int CIN, bool TO_PAD>
__global__ void __launch_bounds__(256)
mfconv3x3(const __hip_bfloat16* __restrict__ Xp, const __hip_bfloat16* __restrict__ Wp,
          __hip_bfloat16* __restrict__ Op, float* __restrict__ Of, int CO) {
  const int lane = threadIdx.x & 63;
  const int wv = threadIdx.x >> 6;
  const int lm = lane & 15;
  const int kg = lane >> 4;                 // 0..3
  const int o0 = blockIdx.x * 64;
  const int b = blockIdx.z;
  const int p0 = blockIdx.y * 128 + wv * 32;

  int px[2], yy[2], xx[2], poff[2];
#pragma unroll
  for (int g = 0; g < 2; ++g) {
    px[g] = p0 + g * 16 + lm;
    yy[g] = px[g] / 48; xx[g] = px[g] - yy[g] * 48;
    poff[g] = ((b * 50 + yy[g] + 1) * 50 + (xx[g] + 1)) * CIN + kg * 8;
  }

  f32x4 acc[4][2];
#pragma unroll
  for (int f = 0; f < 4; ++f)
#pragma unroll
    for (int g = 0; g < 2; ++g) acc[f][g] = (f32x4){0.f, 0.f, 0.f, 0.f};

  const __hip_bfloat16* Wbase = Wp + (size_t)(o0 + lm) * CIN + kg * 8;

  for (int tap = 0; tap < 9; ++tap) {
    const int dy = tap / 3 - 1, dx = tap - (tap / 3) * 3 - 1;
    const int toff = (dy * 50 + dx) * CIN;
    const __hip_bfloat16* Wt = Wbase + (size_t)tap * CO * CIN;
#pragma unroll 4
    for (int c0 = 0; c0 < CIN; c0 += 32) {
      bf16x8 a[4], bb[2];
#pragma unroll
      for (int f = 0; f < 4; ++f)
        a[f] = *(const bf16x8*)(Wt + f * 16 * CIN + c0);
#pragma unroll
      for (int g = 0; g < 2; ++g)
        bb[g] = *(const bf16x8*)(Xp + poff[g] + toff + c0);
#pragma unroll
      for (int f = 0; f < 4; ++f)
#pragma unroll
        for (int g = 0; g < 2; ++g)
          acc[f][g] = __builtin_amdgcn_mfma_f32_16x16x32_bf16(a[f], bb[g], acc[f][g], 0, 0, 0);
    }
  }

#pragma unroll
  for (int f = 0; f < 4; ++f)
#pragma unroll
    for (int g = 0; g < 2; ++g) {
#pragma unroll
      for (int r = 0; r < 4; ++r) {
        int o = o0 + f * 16 + kg * 4 + r;
        float v = acc[f][g][r];
        if (TO_PAD) {
          v = v / (1.f + __expf(-v));
          Op[((size_t)(b * 50 + yy[g] + 1) * 50 + (xx[g] + 1)) * CO + o] = __float2bfloat16(v);
        } else {
          Of[((size_t)b * CO + o) * HW + px[g]] = v;
        }
      }
    }
}

extern "C" void kernel_launch(void* const* d_in, const int* in_sizes, int n_in,
                              void* d_out, int out_size, void* d_ws, size_t ws_size,
                              hipStream_t stream) {
  (void)in_sizes; (void)n_in; (void)out_size; (void)ws_size;
  const float* x      = (const float*)d_in[0];
  const float* cond   = (const float*)d_in[1];
  const float* gn_w   = (const float*)d_in[2];
  const float* gn_b   = (const float*)d_in[3];
  const float* q_dw   = (const float*)d_in[4];
  const float* q_pw_w = (const float*)d_in[5];
  const float* q_pw_b = (const float*)d_in[6];
  const float* kv_dw  = (const float*)d_in[7];
  const float* kv_pw_w= (const float*)d_in[8];
  const float* kv_pw_b= (const float*)d_in[9];
  const float* ao_w   = (const float*)d_in[10];
  const float* ao_b   = (const float*)d_in[11];
  const float* w1     = (const float*)d_in[12];
  const float* w2     = (const float*)d_in[13];
  const float* w3     = (const float*)d_in[14];
  const float* b3     = (const float*)d_in[15];
  float* ws = (float*)d_ws;
  float* Yo = (float*)d_out;

  const size_t U = 2359296;   // 4*256*48*48 (floats)
  const size_t Hf = 1228800;  // 4*256*48*25 (floats)
  const size_t CS = 589824;   // 256*2304
  const size_t CS2 = 1179648; // 512*2304

  float* XN  = ws;             // [0,U)
  float* DW  = ws + U;
  float* Qb  = ws + 2 * U;
  float* KV  = ws + 3 * U;     // 2U extent
  // bf16 spectra: 6 tensors of 1,228,800 bf16 (= Hf/2 floats each) at [5U, 5U+3Hf)
  __hip_bfloat16* AQT = (__hip_bfloat16*)(ws + 5 * U);
  __hip_bfloat16* PQT = AQT + 1228800;
  __hip_bfloat16* AKT = AQT + 2 * 1228800;
  __hip_bfloat16* PKT = AQT + 3 * 1228800;
  __hip_bfloat16* AVc = AQT + 4 * 1228800;
  __hip_bfloat16* PVc = AQT + 5 * 1228800;
  float* AO  = ws + 5 * U + 3 * Hf;   // f32 attn outputs [5U+3Hf, 5U+5Hf)
  float* PO  = AO + Hf;
  float* OUT = ws + U;
  float* ATT = ws + 5 * U;     // overlaps dead spectra (not AO/PO)
  __hip_bfloat16* Xp1 = (__hip_bfloat16*)(ws + U);
  __hip_bfloat16* Xp2 = (__hip_bfloat16*)(ws + 2 * U);
  __hip_bfloat16* Wp1 = (__hip_bfloat16*)(ws + 2 * U + 2600000);
  __hip_bfloat16* Wp2 = (__hip_bfloat16*)(ws + 2 * U + 3200000);
  float* H2  = ws;

  // 1. GroupNorm
  gn_kernel<<<128, 256, 0, stream>>>(x, gn_w, gn_b, XN);
  // 2-3. q path
  dw3x3_kernel<<<1024, 256, 0, stream>>>(XN, q_dw, DW);
  pw_kernel<false><<<dim3(3, 64, 4), 256, 0, stream>>>(DW, CS, q_pw_w, q_pw_b, nullptr, 0, Qb, CS);
  // 4-5. kv path
  dw3x3_kernel<<<1024, 256, 0, stream>>>(cond, kv_dw, DW);
  pw_kernel<false><<<dim3(3, 128, 4), 256, 0, stream>>>(DW, CS, kv_pw_w, kv_pw_b, nullptr, 0, KV, CS2);
  // 6. L2 norm (q, k, v)
  l2n_kernel<<<dim3(9, 4), 256, 0, stream>>>(Qb, CS);
  l2n_kernel<<<dim3(9, 4), 256, 0, stream>>>(KV, CS2);
  l2n_kernel<<<dim3(9, 4), 256, 0, stream>>>(KV + CS, CS2);
  // 7. rfft2 + abs/angle -> bf16 (Q,K token-major; V channel-major)
  rfft2_kernel<true ><<<1024, 256, 0, stream>>>(Qb, CS, AQT, PQT);
  rfft2_kernel<true ><<<1024, 256, 0, stream>>>(KV, CS2, AKT, PKT);
  rfft2_kernel<false><<<1024, 256, 0, stream>>>(KV + CS, CS2, AVc, PVc);
  // 8. MFMA attention on amplitude and phase
  attn_mfma<<<dim3(75, 32), 64, 0, stream>>>(AQT, AKT, AVc, AO);
  attn_mfma<<<dim3(75, 32), 64, 0, stream>>>(PQT, PKT, PVc, PO);
  // 9. polar + irfft2
  polar_irfft2_kernel<<<1024, 256, 0, stream>>>(AO, PO, OUT);
  // 10. attn_out = 1x1(out) + b + xn  -> ATT
  pw_kernel<true><<<dim3(3, 64, 4), 256, 0, stream>>>(OUT, CS, ao_w, ao_b, XN, CS, ATT, CS);
  // 11. FFN via bf16 MFMA
  hipMemsetAsync(Xp1, 0, 2560000 * sizeof(__hip_bfloat16), stream);
  hipMemsetAsync(Xp2, 0, 5120000 * sizeof(__hip_bfloat16), stream);
  packx_kernel<<<dim3(48, 4), 256, 0, stream>>>(ATT, Xp1);
  packw_kernel<256><<<512, 256, 0, stream>>>(w1, Wp1, 512);
  packw_kernel<512><<<512, 256, 0, stream>>>(w2, Wp2, 256);
  mfconv3x3<256, true><<<dim3(8, 18, 4), 256, 0, stream>>>(Xp1, Wp1, Xp2, nullptr, 512);
  mfconv3x3<512, false><<<dim3(4, 18, 4), 256, 0, stream>>>(Xp2, Wp2, nullptr, H2, 256);
  // 12. out = 1x1(h2) + b3 + attn_out
  pw_kernel<true><<<dim3(3, 64, 4), 256, 0, stream>>>(H2, CS, w3, b3, ATT, CS, Yo, CS);
}